// Round 6
// baseline (119.899 us; speedup 1.0000x reference)
//
#include <hip/hip_runtime.h>

typedef __attribute__((ext_vector_type(8))) short bf16x8;
typedef __attribute__((ext_vector_type(4))) short bf16x4;
typedef __attribute__((ext_vector_type(4))) float f32x4;

#define B_NUM 2048
#define F_NUM 40
#define E_DIM 32
#define P_NUM 780
#define D_DIM 16
#define PC_N  65            // pair chunks
#define PC_SZ 12            // 65*12 = 780 exactly
#define LN_EPS 1e-3f

// workspace layout (bytes)
#define XB_OFF 0
#define XB_BYTES (B_NUM * F_NUM * E_DIM * 2)     // 5.24 MB bf16 x, row-major [b][f][e]
#define WF_OFF XB_BYTES
#define WF_BYTES (P_NUM * 2 * 64 * 8 * 2)        // 1.6 MB f-permuted W fragments
#define HP_OFF (WF_OFF + WF_BYTES)               // hpart f32 [PC_N][B][D] = 8.5 MB

static __device__ __forceinline__ unsigned short f2b(float f) {
  unsigned u = __builtin_bit_cast(unsigned, f);
  u += 0x7fffu + ((u >> 16) & 1u);               // round-to-nearest-even
  return (unsigned short)(u >> 16);
}

// ---------------------------------------------------------------------------
// Prep: x -> bf16 row-major; W -> per-lane A-fragments with f-PERMUTED m-rows.
// A-frag (16x16x32): lane l holds A[m = l&15][k = (l>>4)*8 + t].
// m -> f_orig = (m>>2)*8 + frag*4 + (m&3), so C-row m=lhi*4+r maps to
// f_orig = lhi*8 + frag*4 + r: the lane's 8 xj values are contiguous.
__global__ __launch_bounds__(256) void prep_kernel(
    const float* __restrict__ x, const float* __restrict__ W,
    short* __restrict__ xb, short* __restrict__ wfrag) {
  const int lane = threadIdx.x & 63;
  const int wv   = threadIdx.x >> 6;
  const int lhi = lane >> 4, llo = lane & 15;
  __shared__ float wst[4][E_DIM * E_DIM];        // 16 KB, one W_p per wave

  if (blockIdx.x < 2560) {
    const size_t idx = ((size_t)blockIdx.x * 256 + threadIdx.x) * 4;
    float4 v = *reinterpret_cast<const float4*>(x + idx);
    bf16x4 o;
    o[0] = (short)f2b(v.x); o[1] = (short)f2b(v.y);
    o[2] = (short)f2b(v.z); o[3] = (short)f2b(v.w);
    *reinterpret_cast<bf16x4*>(xb + idx) = o;
  } else {
    const int p = (blockIdx.x - 2560) * 4 + wv;
    const float* Wp = W + (size_t)p * (E_DIM * E_DIM);
#pragma unroll
    for (int k = 0; k < 4; ++k) {
      float4 v = *reinterpret_cast<const float4*>(Wp + k * 256 + lane * 4);
      *reinterpret_cast<float4*>(&wst[wv][k * 256 + lane * 4]) = v;
    }
#pragma unroll
    for (int frag = 0; frag < 2; ++frag) {
      const int fo = (llo >> 2) * 8 + frag * 4 + (llo & 3);   // permuted f
      bf16x8 v;
#pragma unroll
      for (int t = 0; t < 8; ++t)
        v[t] = (short)f2b(wst[wv][(lhi * 8 + t) * E_DIM + fo]);
      *reinterpret_cast<bf16x8*>(wfrag + ((size_t)(p * 2 + frag) * 64 + lane) * 8) = v;
    }
  }
}

// ---------------------------------------------------------------------------
// Fused: p = xi' W xj via MFMA, folded into h += p * dw[p] with the cross-lane
// reduction DEFERRED to kernel end (no shuffles in the pair loop).
// grid (2048/128, 65), block 256 = 4 waves; wave = 32 batches (2 n-tiles).
__global__ __launch_bounds__(256, 3) void fused_bilinear_dense_kernel(
    const float* __restrict__ xf, const short* __restrict__ xb,
    const short* __restrict__ wfrag, const float* __restrict__ dw,
    float* __restrict__ hpart) {
  __shared__ short alds[PC_SZ * 2 * 512];        // 24 KB a-frags for the chunk
  const int lane = threadIdx.x & 63;
  const int wv   = threadIdx.x >> 6;
  const int lhi = lane >> 4, llo = lane & 15;
  const int bb = blockIdx.x * 128 + wv * 32;
  const int pc = blockIdx.y;
  const int p0 = pc * PC_SZ;

  // stage a-frags: wave wv copies segments [6wv, 6wv+6) (1 KB each)
#pragma unroll
  for (int s = 0; s < 6; ++s) {
    const int seg = wv * 6 + s;
    bf16x8 v = *reinterpret_cast<const bf16x8*>(
        wfrag + ((size_t)(p0 * 2 + seg) * 64 + lane) * 8);
    *reinterpret_cast<bf16x8*>(&alds[seg * 512 + lane * 8]) = v;
  }
  __syncthreads();

  const short* xbrow0 = xb + (size_t)(bb + llo) * (F_NUM * E_DIM) + lhi * 8;
  const short* xbrow1 = xbrow0 + 16 * (F_NUM * E_DIM);
  const float* xfrow0 = xf + (size_t)(bb + llo) * (F_NUM * E_DIM) + lhi * 8;
  const float* xfrow1 = xfrow0 + 16 * (F_NUM * E_DIM);

  float h0[D_DIM], h1[D_DIM];                    // per-lane f-quarter partials
#pragma unroll
  for (int d = 0; d < D_DIM; ++d) { h0[d] = 0.f; h1[d] = 0.f; }

  // locate (i,j) of pair p0 in combinations(range(40),2) order
  int i = 0;
  while ((i + 1) * (79 - (i + 1)) / 2 <= p0) ++i;
  int j = i + 1 + (p0 - i * (79 - i) / 2);

  bf16x8 bf0 = *reinterpret_cast<const bf16x8*>(xbrow0 + i * E_DIM);
  bf16x8 bf1 = *reinterpret_cast<const bf16x8*>(xbrow1 + i * E_DIM);
  float4 xc0a = *reinterpret_cast<const float4*>(xfrow0 + j * E_DIM);
  float4 xc0b = *reinterpret_cast<const float4*>(xfrow0 + j * E_DIM + 4);
  float4 xc1a = *reinterpret_cast<const float4*>(xfrow1 + j * E_DIM);
  float4 xc1b = *reinterpret_cast<const float4*>(xfrow1 + j * E_DIM + 4);

#pragma unroll
  for (int pl = 0; pl < PC_SZ; ++pl) {
    const int p = p0 + pl;
    // ---- prefetch next pair's xj (and bf on i-change) ----
    int in_ = i, jn = j + 1;
    if (jn == F_NUM) { in_ = i + 1; jn = in_ + 1; }
    float4 nx0a = xc0a, nx0b = xc0b, nx1a = xc1a, nx1b = xc1b;
    bf16x8 nbf0 = bf0, nbf1 = bf1;
    if (pl < PC_SZ - 1) {
      nx0a = *reinterpret_cast<const float4*>(xfrow0 + jn * E_DIM);
      nx0b = *reinterpret_cast<const float4*>(xfrow0 + jn * E_DIM + 4);
      nx1a = *reinterpret_cast<const float4*>(xfrow1 + jn * E_DIM);
      nx1b = *reinterpret_cast<const float4*>(xfrow1 + jn * E_DIM + 4);
      if (in_ != i) {
        nbf0 = *reinterpret_cast<const bf16x8*>(xbrow0 + in_ * E_DIM);
        nbf1 = *reinterpret_cast<const bf16x8*>(xbrow1 + in_ * E_DIM);
      }
    }
    // ---- compute current pair ----
    const bf16x8 a0 = *reinterpret_cast<const bf16x8*>(&alds[(pl * 2 + 0) * 512 + lane * 8]);
    const bf16x8 a1 = *reinterpret_cast<const bf16x8*>(&alds[(pl * 2 + 1) * 512 + lane * 8]);
    f32x4 z = {0.f, 0.f, 0.f, 0.f};
    f32x4 c00 = __builtin_amdgcn_mfma_f32_16x16x32_bf16(a0, bf0, z, 0, 0, 0);
    f32x4 c01 = __builtin_amdgcn_mfma_f32_16x16x32_bf16(a1, bf0, z, 0, 0, 0);
    f32x4 c10 = __builtin_amdgcn_mfma_f32_16x16x32_bf16(a0, bf1, z, 0, 0, 0);
    f32x4 c11 = __builtin_amdgcn_mfma_f32_16x16x32_bf16(a1, bf1, z, 0, 0, 0);

    // tree dot over this lane's 8 f-values (fp32 xj)
    const float s0 = ((c00[0] * xc0a.x + c00[1] * xc0a.y) +
                      (c00[2] * xc0a.z + c00[3] * xc0a.w)) +
                     ((c01[0] * xc0b.x + c01[1] * xc0b.y) +
                      (c01[2] * xc0b.z + c01[3] * xc0b.w));
    const float s1 = ((c10[0] * xc1a.x + c10[1] * xc1a.y) +
                      (c10[2] * xc1a.z + c10[3] * xc1a.w)) +
                     ((c11[0] * xc1b.x + c11[1] * xc1b.y) +
                      (c11[2] * xc1b.z + c11[3] * xc1b.w));

    // fold dense row p (wave-uniform -> scalar loads), static indices only
    const float* __restrict__ dws = dw + __builtin_amdgcn_readfirstlane(p) * D_DIM;
#pragma unroll
    for (int d = 0; d < D_DIM; ++d) {
      h0[d] = fmaf(s0, dws[d], h0[d]);
      h1[d] = fmaf(s1, dws[d], h1[d]);
    }
    // ---- rotate pipeline ----
    i = in_; j = jn;
    xc0a = nx0a; xc0b = nx0b; xc1a = nx1a; xc1b = nx1b;
    bf0 = nbf0; bf1 = nbf1;
  }

  // one-time cross-lhi completion (f-quarters live in lane groups ±16, ±32)
#pragma unroll
  for (int d = 0; d < D_DIM; ++d) {
    float v = h0[d]; v += __shfl_xor(v, 16); v += __shfl_xor(v, 32); h0[d] = v;
    float w = h1[d]; w += __shfl_xor(w, 16); w += __shfl_xor(w, 32); h1[d] = w;
  }

  // lane stores d-quad [lhi*4, lhi*4+4): select via cndmask (static indices)
#define SEL(H, q) (lhi == 0 ? H[q] : lhi == 1 ? H[4 + q] : lhi == 2 ? H[8 + q] : H[12 + q])
  float* hp = hpart + (size_t)pc * B_NUM * D_DIM;
  *reinterpret_cast<float4*>(hp + (size_t)(bb + llo) * D_DIM + lhi * 4) =
      make_float4(SEL(h0, 0), SEL(h0, 1), SEL(h0, 2), SEL(h0, 3));
  *reinterpret_cast<float4*>(hp + (size_t)(bb + 16 + llo) * D_DIM + lhi * 4) =
      make_float4(SEL(h1, 0), SEL(h1, 1), SEL(h1, 2), SEL(h1, 3));
#undef SEL
}

// ---------------------------------------------------------------------------
// Final: sum 65 h-partials + bias, LayerNorm. grid 128, block 256;
// thread = (b, d): coalesced 1 KB/iter, LN via shfl within 16-lane groups.
__global__ __launch_bounds__(256) void reduce_ln_kernel(
    const float* __restrict__ hpart, const float* __restrict__ bias,
    const float* __restrict__ gamma, const float* __restrict__ beta,
    float* __restrict__ out) {
  const int t = threadIdx.x;
  const int d = t & 15;
  const int b = blockIdx.x * 16 + (t >> 4);
  float acc = bias[d];
  const float* hp = hpart + (size_t)b * D_DIM + d;
#pragma unroll 5
  for (int pc = 0; pc < PC_N; ++pc)
    acc += hp[(size_t)pc * B_NUM * D_DIM];

  float sum = acc;
  sum += __shfl_xor(sum, 1); sum += __shfl_xor(sum, 2);
  sum += __shfl_xor(sum, 4); sum += __shfl_xor(sum, 8);
  const float mu = sum * (1.f / D_DIM);
  const float dev = acc - mu;
  float v = dev * dev;
  v += __shfl_xor(v, 1); v += __shfl_xor(v, 2);
  v += __shfl_xor(v, 4); v += __shfl_xor(v, 8);
  const float rs = rsqrtf(v * (1.f / D_DIM) + LN_EPS);
  out[(size_t)b * D_DIM + d] = dev * rs * gamma[d] + beta[d];
}

extern "C" void kernel_launch(void* const* d_in, const int* in_sizes, int n_in,
                              void* d_out, int out_size, void* d_ws, size_t ws_size,
                              hipStream_t stream) {
  const float* x     = (const float*)d_in[0];
  const float* W     = (const float*)d_in[1];
  const float* dw    = (const float*)d_in[2];
  const float* db    = (const float*)d_in[3];
  const float* gamma = (const float*)d_in[4];
  const float* beta  = (const float*)d_in[5];
  float* out = (float*)d_out;

  short* xb    = (short*)((char*)d_ws + XB_OFF);
  short* wfrag = (short*)((char*)d_ws + WF_OFF);
  float* hpart = (float*)((char*)d_ws + HP_OFF);

  prep_kernel<<<2560 + 195, 256, 0, stream>>>(x, W, xb, wfrag);

  dim3 gA(B_NUM / 128, PC_N);
  fused_bilinear_dense_kernel<<<gA, 256, 0, stream>>>(x, xb, wfrag, dw, hpart);

  reduce_ln_kernel<<<B_NUM / 16, 256, 0, stream>>>(hpart, db, gamma, beta, out);
}

// Round 7
// 52.062 us; speedup vs baseline: 2.3030x; 2.3030x over previous
//
#include <hip/hip_runtime.h>

typedef __attribute__((ext_vector_type(8))) short bf16x8;
typedef __attribute__((ext_vector_type(4))) float f32x4;

#define B_NUM 2048
#define F_NUM 40
#define E_DIM 32
#define P_NUM 780
#define D_DIM 16
#define PC_N  39            // pair chunks
#define PC_SZ 20            // 39*20 = 780 exactly
#define LN_EPS 1e-3f

// workspace layout (bytes)
#define WF_OFF 0
#define WF_BYTES (P_NUM * 2 * 64 * 8 * 2)        // 1.6 MB f-permuted W fragments
#define HP_OFF WF_BYTES                          // hpart f32 [PC_N][B][D] = 5.1 MB

static __device__ __forceinline__ unsigned short f2b(float f) {
  unsigned u = __builtin_bit_cast(unsigned, f);
  u += 0x7fffu + ((u >> 16) & 1u);               // round-to-nearest-even
  return (unsigned short)(u >> 16);
}
static __device__ __forceinline__ short f2bs(float f) { return (short)f2b(f); }

static __device__ __forceinline__ bf16x8 pack8(float4 a, float4 b) {
  bf16x8 v;
  v[0] = f2bs(a.x); v[1] = f2bs(a.y); v[2] = f2bs(a.z); v[3] = f2bs(a.w);
  v[4] = f2bs(b.x); v[5] = f2bs(b.y); v[6] = f2bs(b.z); v[7] = f2bs(b.w);
  return v;
}

// ---------------------------------------------------------------------------
// Prep: W -> per-lane A-fragments with f-PERMUTED m-rows (via LDS transpose).
// A-frag (16x16x32): lane l holds A[m = l&15][k = (l>>4)*8 + t].
// m -> fo = (m>>2)*8 + frag*4 + (m&3): C-row m=lhi*4+r maps to
// fo = lhi*8 + frag*4 + r, so one lane's 8 f-slots are contiguous [lhi*8, +8).
// grid 195 blocks, one pair per wave.
__global__ __launch_bounds__(256) void prep_kernel(
    const float* __restrict__ W, short* __restrict__ wfrag) {
  const int lane = threadIdx.x & 63;
  const int wv   = threadIdx.x >> 6;
  const int lhi = lane >> 4, llo = lane & 15;
  __shared__ float wst[4][E_DIM * E_DIM];        // 16 KB, one W_p per wave

  const int p = blockIdx.x * 4 + wv;
  const float* Wp = W + (size_t)p * (E_DIM * E_DIM);
#pragma unroll
  for (int k = 0; k < 4; ++k) {
    float4 v = *reinterpret_cast<const float4*>(Wp + k * 256 + lane * 4);
    *reinterpret_cast<float4*>(&wst[wv][k * 256 + lane * 4]) = v;
  }
  // same-wave LDS RAW: compiler inserts lgkmcnt wait; no barrier needed
#pragma unroll
  for (int frag = 0; frag < 2; ++frag) {
    const int fo = (llo >> 2) * 8 + frag * 4 + (llo & 3);   // permuted f
    bf16x8 v;
#pragma unroll
    for (int t = 0; t < 8; ++t)
      v[t] = f2bs(wst[wv][(lhi * 8 + t) * E_DIM + fo]);     // A[m][k]=W[e=k][fo]
    *reinterpret_cast<bf16x8*>(wfrag + ((size_t)(p * 2 + frag) * 64 + lane) * 8) = v;
  }
}

// ---------------------------------------------------------------------------
// Fused dual-MFMA: MFMA1 computes t[fo,b] = (W_p^T xi); u = t*xj is (after
// bf16 convert) EXACTLY the B-fragment of MFMA2, whose A-operand is dw[p,d]
// replicated over k. MFMA2's K-reduction performs the f-sum AND the dense
// fold, accumulating h[d,b] over all 20 pairs in one f32x4 per n-tile.
// No shuffles, no LDS, no register arrays. grid (16, 39), block 256.
__global__ __launch_bounds__(256) void fused_bilinear_dense_kernel(
    const float* __restrict__ xf, const short* __restrict__ wfrag,
    const float* __restrict__ dw, float* __restrict__ hpart) {
  const int lane = threadIdx.x & 63;
  const int wv   = threadIdx.x >> 6;
  const int lhi = lane >> 4, llo = lane & 15;
  const int bb = blockIdx.x * 128 + wv * 32;
  const int pc = blockIdx.y;
  const int p0 = pc * PC_SZ;

  // per-lane fp32 x row bases; both xi (k=e) and xj (k=fo) use + lhi*8
  const float* xfrow0 = xf + (size_t)(bb + llo) * (F_NUM * E_DIM) + lhi * 8;
  const float* xfrow1 = xfrow0 + 16 * (F_NUM * E_DIM);

  // locate (i,j) of pair p0 in combinations(range(40),2) order
  int i = 0;
  while ((i + 1) * (79 - (i + 1)) / 2 <= p0) ++i;
  int j = i + 1 + (p0 - i * (79 - i) / 2);

  bf16x8 bf0 = pack8(*reinterpret_cast<const float4*>(xfrow0 + i * E_DIM),
                     *reinterpret_cast<const float4*>(xfrow0 + i * E_DIM + 4));
  bf16x8 bf1 = pack8(*reinterpret_cast<const float4*>(xfrow1 + i * E_DIM),
                     *reinterpret_cast<const float4*>(xfrow1 + i * E_DIM + 4));

  f32x4 acc0 = {0.f, 0.f, 0.f, 0.f};
  f32x4 acc1 = {0.f, 0.f, 0.f, 0.f};
  const f32x4 z = {0.f, 0.f, 0.f, 0.f};

#pragma unroll
  for (int pl = 0; pl < PC_SZ; ++pl) {
    const int p = p0 + pl;
    const bf16x8 a0 = *reinterpret_cast<const bf16x8*>(
        wfrag + ((size_t)(p * 2 + 0) * 64 + lane) * 8);
    const bf16x8 a1 = *reinterpret_cast<const bf16x8*>(
        wfrag + ((size_t)(p * 2 + 1) * 64 + lane) * 8);
    // A2 fragment: dw[p, m=llo] broadcast into all 8 k-slots
    const short dwb = f2bs(dw[p * D_DIM + llo]);
    bf16x8 a2;
#pragma unroll
    for (int t = 0; t < 8; ++t) a2[t] = dwb;

    const float4 xj0a = *reinterpret_cast<const float4*>(xfrow0 + j * E_DIM);
    const float4 xj0b = *reinterpret_cast<const float4*>(xfrow0 + j * E_DIM + 4);
    const float4 xj1a = *reinterpret_cast<const float4*>(xfrow1 + j * E_DIM);
    const float4 xj1b = *reinterpret_cast<const float4*>(xfrow1 + j * E_DIM + 4);

    const f32x4 c00 = __builtin_amdgcn_mfma_f32_16x16x32_bf16(a0, bf0, z, 0, 0, 0);
    const f32x4 c01 = __builtin_amdgcn_mfma_f32_16x16x32_bf16(a1, bf0, z, 0, 0, 0);
    const f32x4 c10 = __builtin_amdgcn_mfma_f32_16x16x32_bf16(a0, bf1, z, 0, 0, 0);
    const f32x4 c11 = __builtin_amdgcn_mfma_f32_16x16x32_bf16(a1, bf1, z, 0, 0, 0);

    // u[k=lhi*8+t][b=llo] = t * xj  -> B-fragment of MFMA2 (slot t == fo order)
    bf16x8 u0, u1;
    u0[0] = f2bs(c00[0] * xj0a.x); u0[1] = f2bs(c00[1] * xj0a.y);
    u0[2] = f2bs(c00[2] * xj0a.z); u0[3] = f2bs(c00[3] * xj0a.w);
    u0[4] = f2bs(c01[0] * xj0b.x); u0[5] = f2bs(c01[1] * xj0b.y);
    u0[6] = f2bs(c01[2] * xj0b.z); u0[7] = f2bs(c01[3] * xj0b.w);
    u1[0] = f2bs(c10[0] * xj1a.x); u1[1] = f2bs(c10[1] * xj1a.y);
    u1[2] = f2bs(c10[2] * xj1a.z); u1[3] = f2bs(c10[3] * xj1a.w);
    u1[4] = f2bs(c11[0] * xj1b.x); u1[5] = f2bs(c11[1] * xj1b.y);
    u1[6] = f2bs(c11[2] * xj1b.z); u1[7] = f2bs(c11[3] * xj1b.w);

    // h[d,b] += sum_k u * dw : f-reduction + dense fold inside the MFMA
    acc0 = __builtin_amdgcn_mfma_f32_16x16x32_bf16(a2, u0, acc0, 0, 0, 0);
    acc1 = __builtin_amdgcn_mfma_f32_16x16x32_bf16(a2, u1, acc1, 0, 0, 0);

    if (++j == F_NUM) {
      ++i; j = i + 1;
      bf0 = pack8(*reinterpret_cast<const float4*>(xfrow0 + i * E_DIM),
                  *reinterpret_cast<const float4*>(xfrow0 + i * E_DIM + 4));
      bf1 = pack8(*reinterpret_cast<const float4*>(xfrow1 + i * E_DIM),
                  *reinterpret_cast<const float4*>(xfrow1 + i * E_DIM + 4));
    }
  }

  // C2 layout: lane holds b = llo, d = lhi*4 + r  -> coalesced float4 stores
  float* hp = hpart + (size_t)pc * B_NUM * D_DIM;
  *reinterpret_cast<f32x4*>(hp + (size_t)(bb + llo) * D_DIM + lhi * 4) = acc0;
  *reinterpret_cast<f32x4*>(hp + (size_t)(bb + 16 + llo) * D_DIM + lhi * 4) = acc1;
}

// ---------------------------------------------------------------------------
// Final: sum 39 h-partials + bias, LayerNorm. grid 128, block 256;
// thread = (b, d): coalesced 1 KB/iter, LN via shfl within 16-lane groups.
__global__ __launch_bounds__(256) void reduce_ln_kernel(
    const float* __restrict__ hpart, const float* __restrict__ bias,
    const float* __restrict__ gamma, const float* __restrict__ beta,
    float* __restrict__ out) {
  const int t = threadIdx.x;
  const int d = t & 15;
  const int b = blockIdx.x * 16 + (t >> 4);
  float acc = bias[d];
  const float* hp = hpart + (size_t)b * D_DIM + d;
#pragma unroll 3
  for (int pc = 0; pc < PC_N; ++pc)
    acc += hp[(size_t)pc * B_NUM * D_DIM];

  float sum = acc;
  sum += __shfl_xor(sum, 1); sum += __shfl_xor(sum, 2);
  sum += __shfl_xor(sum, 4); sum += __shfl_xor(sum, 8);
  const float mu = sum * (1.f / D_DIM);
  const float dev = acc - mu;
  float v = dev * dev;
  v += __shfl_xor(v, 1); v += __shfl_xor(v, 2);
  v += __shfl_xor(v, 4); v += __shfl_xor(v, 8);
  const float rs = rsqrtf(v * (1.f / D_DIM) + LN_EPS);
  out[(size_t)b * D_DIM + d] = dev * rs * gamma[d] + beta[d];
}

extern "C" void kernel_launch(void* const* d_in, const int* in_sizes, int n_in,
                              void* d_out, int out_size, void* d_ws, size_t ws_size,
                              hipStream_t stream) {
  const float* x     = (const float*)d_in[0];
  const float* W     = (const float*)d_in[1];
  const float* dw    = (const float*)d_in[2];
  const float* db    = (const float*)d_in[3];
  const float* gamma = (const float*)d_in[4];
  const float* beta  = (const float*)d_in[5];
  float* out = (float*)d_out;

  short* wfrag = (short*)((char*)d_ws + WF_OFF);
  float* hpart = (float*)((char*)d_ws + HP_OFF);

  prep_kernel<<<P_NUM / 4, 256, 0, stream>>>(W, wfrag);

  dim3 gA(B_NUM / 128, PC_N);
  fused_bilinear_dense_kernel<<<gA, 256, 0, stream>>>(x, wfrag, dw, hpart);

  reduce_ln_kernel<<<B_NUM / 16, 256, 0, stream>>>(hpart, db, gamma, beta, out);
}

// Round 8
// 35.748 us; speedup vs baseline: 3.3540x; 1.4564x over previous
//
#include <hip/hip_runtime.h>

typedef __attribute__((ext_vector_type(8))) short bf16x8;
typedef __attribute__((ext_vector_type(4))) float f32x4;

#define B_NUM 2048
#define F_NUM 40
#define E_DIM 32
#define P_NUM 780
#define D_DIM 16
#define PC_N  78            // pair chunks
#define PC_SZ 10            // 78*10 = 780 exactly
#define LN_EPS 1e-3f

// workspace layout (bytes)
#define WF_OFF 0
#define WF_BYTES (P_NUM * 2 * 64 * 8 * 2)          // 1.6 MB W fragments
#define XJ_OFF  WF_BYTES
#define XJ_BYTES (F_NUM * 4 * B_NUM * 8 * 4)       // 10.5 MB packed f32 x
#define XB_OFF  (XJ_OFF + XJ_BYTES)
#define XB_BYTES (F_NUM * 4 * B_NUM * 8 * 2)       // 5.2 MB packed bf16 x
#define HP_OFF  (XB_OFF + XB_BYTES)                // hpart 78*2048*16*4 = 10.2 MB

static __device__ __forceinline__ unsigned short f2b(float f) {
  unsigned u = __builtin_bit_cast(unsigned, f);
  u += 0x7fffu + ((u >> 16) & 1u);                 // round-to-nearest-even
  return (unsigned short)(u >> 16);
}
static __device__ __forceinline__ short f2bs(float f) { return (short)f2b(f); }

// ---------------------------------------------------------------------------
// Prep:
//  blocks [0,1280): x -> packed [f][e8][b][8] in f32 (xjf) and bf16 (xbp).
//    unit u = ((f*4+e8)*2048 + b); consecutive threads = consecutive b ->
//    writes fully coalesced (reads strided; one-time 21 MB pass).
//  blocks [1280,1475): W -> per-lane A-fragments, f-permuted rows
//    (m -> fo=(m>>2)*8+frag*4+(m&3)), via LDS transpose. One pair per wave.
__global__ __launch_bounds__(256) void prep_kernel(
    const float* __restrict__ x, const float* __restrict__ W,
    float* __restrict__ xjf, short* __restrict__ xbp,
    short* __restrict__ wfrag) {
  const int lane = threadIdx.x & 63;
  const int wv   = threadIdx.x >> 6;
  const int lhi = lane >> 4, llo = lane & 15;
  __shared__ float wst[4][E_DIM * E_DIM];          // 16 KB, one W_p per wave

  if (blockIdx.x < 1280) {
    const int u   = blockIdx.x * 256 + threadIdx.x;
    const int b   = u & (B_NUM - 1);
    const int fe8 = u >> 11;
    const int f = fe8 >> 2, e8 = fe8 & 3;
    const float* src = x + ((size_t)b * F_NUM + f) * E_DIM + e8 * 8;
    const float4 v0 = *reinterpret_cast<const float4*>(src);
    const float4 v1 = *reinterpret_cast<const float4*>(src + 4);
    *reinterpret_cast<float4*>(xjf + (size_t)u * 8)     = v0;
    *reinterpret_cast<float4*>(xjf + (size_t)u * 8 + 4) = v1;
    bf16x8 o;
    o[0] = f2bs(v0.x); o[1] = f2bs(v0.y); o[2] = f2bs(v0.z); o[3] = f2bs(v0.w);
    o[4] = f2bs(v1.x); o[5] = f2bs(v1.y); o[6] = f2bs(v1.z); o[7] = f2bs(v1.w);
    *reinterpret_cast<bf16x8*>(xbp + (size_t)u * 8) = o;
  } else {
    const int p = (blockIdx.x - 1280) * 4 + wv;
    const float* Wp = W + (size_t)p * (E_DIM * E_DIM);
#pragma unroll
    for (int k = 0; k < 4; ++k) {
      float4 v = *reinterpret_cast<const float4*>(Wp + k * 256 + lane * 4);
      *reinterpret_cast<float4*>(&wst[wv][k * 256 + lane * 4]) = v;
    }
    // same-wave LDS RAW: compiler inserts lgkmcnt wait; no barrier needed
#pragma unroll
    for (int frag = 0; frag < 2; ++frag) {
      const int fo = (llo >> 2) * 8 + frag * 4 + (llo & 3);   // permuted f
      bf16x8 v;
#pragma unroll
      for (int t = 0; t < 8; ++t)
        v[t] = f2bs(wst[wv][(lhi * 8 + t) * E_DIM + fo]);     // A[m][k]=W[e=k][fo]
      *reinterpret_cast<bf16x8*>(wfrag + ((size_t)(p * 2 + frag) * 64 + lane) * 8) = v;
    }
  }
}

// ---------------------------------------------------------------------------
// Fused dual-MFMA (round-7 math, coalesced layout + manual 1-deep pipeline):
// MFMA1: t[fo,b] = W_p^T xi ; u = bf16(t * xj) is the B-fragment of MFMA2
// whose A = dw[p,d] replicated over k: MFMA2 performs the f-reduction AND the
// dense fold, accumulating h[d,b] over PC_SZ pairs in one f32x4 per n-tile.
// grid (16, 78), block 256 = 4 waves; wave = 32 batches.
__global__ __launch_bounds__(256, 4) void fused_bilinear_dense_kernel(
    const float* __restrict__ xjf, const short* __restrict__ xbp,
    const short* __restrict__ wfrag, const float* __restrict__ dw,
    float* __restrict__ hpart) {
  const int lane = threadIdx.x & 63;
  const int wv   = threadIdx.x >> 6;
  const int lhi = lane >> 4, llo = lane & 15;
  const int bb = blockIdx.x * 128 + wv * 32;
  const int pc = blockIdx.y;
  const int p0 = pc * PC_SZ;

  // packed-table lane offsets: elem((f*4+lhi)*2048 + b)*8  (+f*65536)
  const int off0 = (lhi * B_NUM + bb + llo) * 8;
  const int off1 = off0 + 16 * 8;
#define XF(f, o) reinterpret_cast<const float4*>(xjf + (size_t)(f) * 65536 + (o))
#define XB8(f, o) reinterpret_cast<const bf16x8*>(xbp + (size_t)(f) * 65536 + (o))
#define AFR(p, fr) reinterpret_cast<const bf16x8*>( \
    wfrag + ((size_t)((p) * 2 + (fr)) * 64 + lane) * 8)

  // locate (i,j) of pair p0 in combinations(range(40),2) order
  int i = 0;
  while ((i + 1) * (79 - (i + 1)) / 2 <= p0) ++i;
  int j = i + 1 + (p0 - i * (79 - i) / 2);

  bf16x8 bf0 = *XB8(i, off0);
  bf16x8 bf1 = *XB8(i, off1);
  bf16x8 a0  = *AFR(p0, 0);
  bf16x8 a1  = *AFR(p0, 1);
  float4 xj0a = XF(j, off0)[0], xj0b = XF(j, off0)[1];
  float4 xj1a = XF(j, off1)[0], xj1b = XF(j, off1)[1];
  short  dwb  = f2bs(dw[p0 * D_DIM + llo]);

  f32x4 acc0 = {0.f, 0.f, 0.f, 0.f};
  f32x4 acc1 = {0.f, 0.f, 0.f, 0.f};
  const f32x4 z = {0.f, 0.f, 0.f, 0.f};

#pragma unroll
  for (int pl = 0; pl < PC_SZ; ++pl) {
    const int p = p0 + pl;
    // ---- next-pair indices + prefetch (issues before the MFMA chain) ----
    int in_ = i, jn = j + 1;
    if (jn == F_NUM) { in_ = i + 1; jn = in_ + 1; }
    bf16x8 a0n = a0, a1n = a1, nbf0 = bf0, nbf1 = bf1;
    float4 nx0a = xj0a, nx0b = xj0b, nx1a = xj1a, nx1b = xj1b;
    short dwbn = dwb;
    if (pl < PC_SZ - 1) {
      a0n = *AFR(p + 1, 0);
      a1n = *AFR(p + 1, 1);
      nx0a = XF(jn, off0)[0]; nx0b = XF(jn, off0)[1];
      nx1a = XF(jn, off1)[0]; nx1b = XF(jn, off1)[1];
      dwbn = f2bs(dw[(p + 1) * D_DIM + llo]);
      if (in_ != i) {                       // wave-uniform branch
        nbf0 = *XB8(in_, off0);
        nbf1 = *XB8(in_, off1);
      }
    }
    // ---- compute current pair ----
    const f32x4 c00 = __builtin_amdgcn_mfma_f32_16x16x32_bf16(a0, bf0, z, 0, 0, 0);
    const f32x4 c01 = __builtin_amdgcn_mfma_f32_16x16x32_bf16(a1, bf0, z, 0, 0, 0);
    const f32x4 c10 = __builtin_amdgcn_mfma_f32_16x16x32_bf16(a0, bf1, z, 0, 0, 0);
    const f32x4 c11 = __builtin_amdgcn_mfma_f32_16x16x32_bf16(a1, bf1, z, 0, 0, 0);

    bf16x8 a2;
#pragma unroll
    for (int t = 0; t < 8; ++t) a2[t] = dwb;

    bf16x8 u0, u1;                          // B-frag of MFMA2: u[k=lhi*8+t]
    u0[0] = f2bs(c00[0] * xj0a.x); u0[1] = f2bs(c00[1] * xj0a.y);
    u0[2] = f2bs(c00[2] * xj0a.z); u0[3] = f2bs(c00[3] * xj0a.w);
    u0[4] = f2bs(c01[0] * xj0b.x); u0[5] = f2bs(c01[1] * xj0b.y);
    u0[6] = f2bs(c01[2] * xj0b.z); u0[7] = f2bs(c01[3] * xj0b.w);
    u1[0] = f2bs(c10[0] * xj1a.x); u1[1] = f2bs(c10[1] * xj1a.y);
    u1[2] = f2bs(c10[2] * xj1a.z); u1[3] = f2bs(c10[3] * xj1a.w);
    u1[4] = f2bs(c11[0] * xj1b.x); u1[5] = f2bs(c11[1] * xj1b.y);
    u1[6] = f2bs(c11[2] * xj1b.z); u1[7] = f2bs(c11[3] * xj1b.w);

    acc0 = __builtin_amdgcn_mfma_f32_16x16x32_bf16(a2, u0, acc0, 0, 0, 0);
    acc1 = __builtin_amdgcn_mfma_f32_16x16x32_bf16(a2, u1, acc1, 0, 0, 0);

    // ---- rotate pipeline ----
    i = in_; j = jn;
    a0 = a0n; a1 = a1n; bf0 = nbf0; bf1 = nbf1;
    xj0a = nx0a; xj0b = nx0b; xj1a = nx1a; xj1b = nx1b;
    dwb = dwbn;
  }
#undef XF
#undef XB8
#undef AFR

  // C2 layout: lane holds b=llo, d=lhi*4+r -> coalesced float4 stores
  float* hp = hpart + (size_t)pc * B_NUM * D_DIM;
  *reinterpret_cast<f32x4*>(hp + (size_t)(bb + llo) * D_DIM + lhi * 4) = acc0;
  *reinterpret_cast<f32x4*>(hp + (size_t)(bb + 16 + llo) * D_DIM + lhi * 4) = acc1;
}

// ---------------------------------------------------------------------------
// Final: sum 78 h-partials + bias, LayerNorm. grid 128, block 256;
// thread = (b, d): per-pc the block reads 1 KB contiguous; unroll-6 prefetch.
__global__ __launch_bounds__(256) void reduce_ln_kernel(
    const float* __restrict__ hpart, const float* __restrict__ bias,
    const float* __restrict__ gamma, const float* __restrict__ beta,
    float* __restrict__ out) {
  const int t = threadIdx.x;
  const int d = t & 15;
  const int b = blockIdx.x * 16 + (t >> 4);
  float acc = bias[d];
  const float* hp = hpart + (size_t)b * D_DIM + d;
#pragma unroll 6
  for (int pc = 0; pc < PC_N; ++pc)
    acc += hp[(size_t)pc * B_NUM * D_DIM];

  float sum = acc;
  sum += __shfl_xor(sum, 1); sum += __shfl_xor(sum, 2);
  sum += __shfl_xor(sum, 4); sum += __shfl_xor(sum, 8);
  const float mu = sum * (1.f / D_DIM);
  const float dev = acc - mu;
  float v = dev * dev;
  v += __shfl_xor(v, 1); v += __shfl_xor(v, 2);
  v += __shfl_xor(v, 4); v += __shfl_xor(v, 8);
  const float rs = rsqrtf(v * (1.f / D_DIM) + LN_EPS);
  out[(size_t)b * D_DIM + d] = dev * rs * gamma[d] + beta[d];
}

extern "C" void kernel_launch(void* const* d_in, const int* in_sizes, int n_in,
                              void* d_out, int out_size, void* d_ws, size_t ws_size,
                              hipStream_t stream) {
  const float* x     = (const float*)d_in[0];
  const float* W     = (const float*)d_in[1];
  const float* dw    = (const float*)d_in[2];
  const float* db    = (const float*)d_in[3];
  const float* gamma = (const float*)d_in[4];
  const float* beta  = (const float*)d_in[5];
  float* out = (float*)d_out;

  short* wfrag = (short*)((char*)d_ws + WF_OFF);
  float* xjf   = (float*)((char*)d_ws + XJ_OFF);
  short* xbp   = (short*)((char*)d_ws + XB_OFF);
  float* hpart = (float*)((char*)d_ws + HP_OFF);

  prep_kernel<<<1280 + 195, 256, 0, stream>>>(x, W, xjf, xbp, wfrag);

  dim3 gA(B_NUM / 128, PC_N);
  fused_bilinear_dense_kernel<<<gA, 256, 0, stream>>>(xjf, xbp, wfrag, dw, hpart);

  reduce_ln_kernel<<<B_NUM / 16, 256, 0, stream>>>(hpart, db, gamma, beta, out);
}